// Round 1
// baseline (231.352 us; speedup 1.0000x reference)
//
#include <hip/hip_runtime.h>

// NonSpikingInput: RK2 leaky integrator, closed form per step:
//   v' = 0.625*v + 0.075*i   (E_REST = I_BIAS = 0)
// Output = full history, (4096, 8192) fp32. Memory-bound: 268 MB -> ~43 us floor.
//
// R3 state: LDS round-trip for coalesced loads AND stores, padded chunks
// (32 floats + 4 pad = 144 B stride, conflict-free b128). 80.7 us dispatch,
// 2.5 TB/s -- serialization-bound, not BW-bound (VALUBusy 8%, conflicts nil).
//
// R4 change: one-shot block (load -> syncthreads -> scan -> syncthreads ->
// store -> endpgm) never overlaps reads with writes: __syncthreads drains
// vmcnt(0), and the 4 occupancy rounds each pay a fresh HBM latency ramp.
// -> persistent 4-row pipeline per block (grid 1024, all resident at t=0):
//    * ping-pong register staging buf[2][8], j-loop fully unrolled so all
//      indices are static (no scratch); row j+1 loads issue BEFORE row j's
//      scan, hiding load latency under compute+store;
//    * raw s_barrier + explicit "s_waitcnt lgkmcnt(0)" only -- vmcnt is
//      never drained at a barrier, so row j's nontemporal stores retire
//      under row j+1's loads (read/write overlap on HBM).
// Numerics identical to R3 (same op order) -> absmax unchanged.

typedef float fx4 __attribute__((ext_vector_type(4)));

constexpr int TT    = 8192;  // time steps per row
constexpr int BLK   = 256;   // threads per block
constexpr int CHUNK = 32;    // TT / BLK
constexpr int CPAD  = 36;    // padded chunk stride in floats (144 B)

template<int RPB>
__global__ __launch_bounds__(BLK, 4)
void neuron_scan(const float* __restrict__ in, float* __restrict__ out) {
    __shared__ float s[BLK * CPAD];  // 36 KiB -> 4 blocks/CU
    const float A = 0.625f;
    const float B = 0.075f;

    const int t = threadIdx.x;
    const size_t row_stride = (size_t)gridDim.x * TT;

    fx4 buf[2][8];   // ping-pong staging; statically indexed after unroll

    // Prologue: issue row-0 loads (coalesced float4).
    {
        const fx4* src = (const fx4*)(in + (size_t)blockIdx.x * TT);
        #pragma unroll
        for (int k = 0; k < 8; ++k) buf[0][k] = src[t + BLK * k];
    }

    size_t row = (size_t)blockIdx.x * TT;

    #pragma unroll
    for (int j = 0; j < RPB; ++j) {
        fx4* cur = buf[j & 1];
        fx4* nxt = buf[(j + 1) & 1];

        // Issue next row's loads early: latency hides under this row's
        // scan + store. (vmcnt waits below are incremental, so these stay
        // in flight across the barriers.)
        if (j + 1 < RPB) {
            const fx4* src = (const fx4*)(in + row + row_stride);
            #pragma unroll
            for (int k = 0; k < 8; ++k) nxt[k] = src[t + BLK * k];
        }

        // Phase 1: regs -> LDS, padded layout (waits cur's loads only).
        #pragma unroll
        for (int k = 0; k < 8; ++k) {
            const int o = (t + BLK * k) << 2;   // logical float offset
            *(fx4*)(s + (o >> 5) * CPAD + (o & 31)) = cur[k];
        }
        asm volatile("s_waitcnt lgkmcnt(0)" ::: "memory");
        __builtin_amdgcn_s_barrier();

        // Phase 2: 64-step warm-up over the two preceding chunks.
        float v = 0.0f;
        #pragma unroll
        for (int w = 2; w >= 1; --w) {
            const int c = t - w;
            const fx4* p = (const fx4*)(s + (c < 0 ? 0 : c * CPAD));
            const float b = (c >= 0) ? B : 0.0f;  // b=0 keeps v exactly 0 at edge
            #pragma unroll
            for (int q = 0; q < 8; ++q) {
                const fx4 x = p[q];
                v = fmaf(A, v, b * x.x);
                v = fmaf(A, v, b * x.y);
                v = fmaf(A, v, b * x.z);
                v = fmaf(A, v, b * x.w);
            }
        }
        asm volatile("s_waitcnt lgkmcnt(0)" ::: "memory");
        __builtin_amdgcn_s_barrier();   // neighbors' warm-up reads of chunk t
                                        // must finish before t overwrites it

        // Phase 3: in-place scan of own chunk.
        fx4* pc = (fx4*)(s + t * CPAD);
        #pragma unroll
        for (int q = 0; q < 8; ++q) {
            fx4 x = pc[q];
            v = fmaf(A, v, B * x.x); x.x = v;
            v = fmaf(A, v, B * x.y); x.y = v;
            v = fmaf(A, v, B * x.z); x.z = v;
            v = fmaf(A, v, B * x.w); x.w = v;
            pc[q] = x;
        }
        asm volatile("s_waitcnt lgkmcnt(0)" ::: "memory");
        __builtin_amdgcn_s_barrier();

        // Phase 4: coalesced LDS -> global nontemporal store. Only the
        // ds_reads are waited (lgkmcnt); the global stores drain in the
        // background under the next row's work.
        fx4* dst = (fx4*)(out + row);
        #pragma unroll
        for (int k = 0; k < 8; ++k) {
            const int o4 = t + BLK * k;
            const int o = o4 << 2;
            const fx4 val = *(const fx4*)(s + (o >> 5) * CPAD + (o & 31));
            __builtin_nontemporal_store(val, dst + o4);
        }

        if (j + 1 < RPB) {
            // All threads must finish reading LDS before next row's writes.
            asm volatile("s_waitcnt lgkmcnt(0)" ::: "memory");
            __builtin_amdgcn_s_barrier();
        }
        row += row_stride;
    }
}

extern "C" void kernel_launch(void* const* d_in, const int* in_sizes, int n_in,
                              void* d_out, int out_size, void* d_ws, size_t ws_size,
                              hipStream_t stream) {
    const float* in = (const float*)d_in[0];
    float* out = (float*)d_out;
    const int n_rows = in_sizes[0] / TT;   // 4096
    if (n_rows == 4096) {
        // 1024 blocks * 4 rows: exactly 4 blocks/CU resident, one ramp/tail.
        neuron_scan<4><<<dim3(1024), dim3(BLK), 0, stream>>>(in, out);
    } else {
        neuron_scan<1><<<dim3(n_rows), dim3(BLK), 0, stream>>>(in, out);
    }
}

// Round 2
// 228.454 us; speedup vs baseline: 1.0127x; 1.0127x over previous
//
#include <hip/hip_runtime.h>

// NonSpikingInput: RK2 leaky integrator, closed form per step:
//   v' = 0.625*v + 0.075*i   (E_REST = I_BIAS = 0)
// Output = full history, (4096, 8192) fp32. Memory-bound: 268 MB -> ~43 us floor.
//
// R3: LDS round-trip for coalesced loads AND stores, padded chunks. 80.7 us.
// R4 FAILED-NEUTRAL: persistent 4-row pipeline + raw barriers (no vmcnt drain)
//   changed nothing (81.8 us, 2.46 TB/s) -> overlap machinery was not the
//   limiter; both versions had only 16 waves/CU (36 KiB LDS x 4 blocks).
// R5 change: occupancy. Half-row per block (chunk 16, CPAD 20 -> 20 KiB LDS)
//   -> 8 blocks/CU * 4 waves = 32 waves/CU (100% residency), 8192 blocks.
//   Half-row warm-up boundary (64 preceding inputs) lives in the pad HOLES of
//   chunks 0..15 (4 floats each) -> zero extra LDS, ~2 MiB extra reads.
//   Bank math (CPAD=20): scan/warm-up b128 reads: 8 consecutive lanes cover
//   all 32 banks disjointly (minimum aliasing, same as CPAD=36). Numerics
//   identical to R3 (same FMA order, same 64-input warm-up per element).

typedef float fx4 __attribute__((ext_vector_type(4)));

constexpr int TT    = 8192;  // time steps per row
constexpr int BLK   = 256;   // threads per block
constexpr int HALF  = 4096;  // steps per block (half row)
constexpr int CHUNK = 16;    // HALF / BLK
constexpr int CPAD  = 20;    // padded chunk stride in floats (80 B)
constexpr int WARM  = 4;     // warm-up chunks = 64 steps (A^64 ~ 8e-14)

__global__ __launch_bounds__(BLK, 8)
void neuron_scan(const float* __restrict__ in, float* __restrict__ out) {
    __shared__ float s[BLK * CPAD];  // 20480 B -> 8 blocks/CU = 160 KiB exact
    const float A = 0.625f;
    const float B = 0.075f;

    const int t = threadIdx.x;
    const int h = blockIdx.x & 1;    // half index within row (uniform)
    const size_t base = (size_t)(blockIdx.x >> 1) * TT + (size_t)h * HALF;

    // Phase 1: coalesced global -> LDS (padded layout), 4 fx4 per lane.
    const fx4* src = (const fx4*)(in + base);
    #pragma unroll
    for (int k = 0; k < 4; ++k) {
        const int o4 = t + BLK * k;        // float4 index within half-row
        const fx4 val = src[o4];
        const int o = o4 << 2;             // logical float offset
        *(fx4*)(s + (o >> 4) * CPAD + (o & 15)) = val;
    }
    // Boundary stub: the 64 inputs preceding this half-row go into the pad
    // holes of chunks 0..15 (addr l*CPAD+16, one fx4 per hole). h is uniform.
    if (h > 0 && t < 16) {
        const fx4 val = *(const fx4*)(in + base - 64 + 4 * t);
        *(fx4*)(s + t * CPAD + 16) = val;
    }
    __syncthreads();

    // Phase 2: 64-step warm-up over the four preceding chunks.
    float v = 0.0f;
    #pragma unroll
    for (int w = WARM; w >= 1; --w) {
        const int c = t - w;
        if (c >= 0) {
            const fx4* p = (const fx4*)(s + c * CPAD);
            #pragma unroll
            for (int q = 0; q < 4; ++q) {
                const fx4 x = p[q];
                v = fmaf(A, v, B * x.x);
                v = fmaf(A, v, B * x.y);
                v = fmaf(A, v, B * x.z);
                v = fmaf(A, v, B * x.w);
            }
        } else if (h > 0) {
            // chunk c (-4..-1) lives in holes 4*(c+4)+q; only lanes 0..3 ever
            // take this path -> divergence confined to wave 0.
            #pragma unroll
            for (int q = 0; q < 4; ++q) {
                const fx4 x = *(const fx4*)(s + (4 * (c + WARM) + q) * CPAD + 16);
                v = fmaf(A, v, B * x.x);
                v = fmaf(A, v, B * x.y);
                v = fmaf(A, v, B * x.z);
                v = fmaf(A, v, B * x.w);
            }
        }
        // else: true start of row -> v stays exactly 0 (matches reference)
    }
    __syncthreads();   // neighbors' warm-up reads of chunk t must finish
                       // before thread t overwrites it in phase 3

    // Phase 3: in-place scan of own chunk.
    fx4* pc = (fx4*)(s + t * CPAD);
    #pragma unroll
    for (int q = 0; q < 4; ++q) {
        fx4 x = pc[q];
        v = fmaf(A, v, B * x.x); x.x = v;
        v = fmaf(A, v, B * x.y); x.y = v;
        v = fmaf(A, v, B * x.z); x.z = v;
        v = fmaf(A, v, B * x.w); x.w = v;
        pc[q] = x;
    }
    __syncthreads();

    // Phase 4: coalesced LDS -> global nontemporal store (mirror of phase 1).
    fx4* dst = (fx4*)(out + base);
    #pragma unroll
    for (int k = 0; k < 4; ++k) {
        const int o4 = t + BLK * k;
        const int o = o4 << 2;
        const fx4 val = *(const fx4*)(s + (o >> 4) * CPAD + (o & 15));
        __builtin_nontemporal_store(val, dst + o4);
    }
}

extern "C" void kernel_launch(void* const* d_in, const int* in_sizes, int n_in,
                              void* d_out, int out_size, void* d_ws, size_t ws_size,
                              hipStream_t stream) {
    const float* in = (const float*)d_in[0];
    float* out = (float*)d_out;
    const int n_rows = in_sizes[0] / TT;   // 4096
    neuron_scan<<<dim3(n_rows * 2), dim3(BLK), 0, stream>>>(in, out);
}